// Round 1
// baseline (1644.561 us; speedup 1.0000x reference)
//
#include <hip/hip_runtime.h>
#include <math.h>

#define NN 100000
#define DF 512
#define HID 16

// Flag: 1 if edge_index is int64-laid-out, 0 if int32.
__device__ int g_idx64;

__global__ void detect_idx_kernel(const long long* __restrict__ idx) {
    if (threadIdx.x == 0 && blockIdx.x == 0) {
        int ok = 1;
        for (int i = 0; i < 128; ++i) {
            long long v = idx[i];
            if (v < 0 || v >= NN) { ok = 0; break; }
        }
        g_idx64 = ok;
    }
}

// h1 = x @ W1. One wave per node. Lane factored as (kg = lane&15) owning k in
// [kg*32, kg*32+32), (cg = lane>>4) owning cols [cg*4, cg*4+4). W1 fragment
// lives in 128 VGPRs (32 x float4) loaded once per wave; x row streamed with
// coalesced float4 loads; 4-step shfl_xor reduce over the 16 k-lanes.
__global__ __launch_bounds__(256, 2) void gemm1_kernel(
    const float* __restrict__ x, const float* __restrict__ W1,
    float* __restrict__ h1, int nN)
{
    const int lane = threadIdx.x & 63;
    const int waveId = blockIdx.x * (blockDim.x >> 6) + (threadIdx.x >> 6);
    const int nWaves = gridDim.x * (blockDim.x >> 6);
    const int kg = lane & 15;
    const int cg = lane >> 4;

    float4 wf[32];
#pragma unroll
    for (int j = 0; j < 32; ++j)
        wf[j] = *(const float4*)&W1[(kg * 32 + j) * HID + cg * 4];

    for (int node = waveId; node < nN; node += nWaves) {
        const float4* xr = (const float4*)&x[(size_t)node * DF + kg * 32];
        float4 xv[8];
#pragma unroll
        for (int j = 0; j < 8; ++j) xv[j] = xr[j];

        float4 acc = make_float4(0.f, 0.f, 0.f, 0.f);
#pragma unroll
        for (int j = 0; j < 8; ++j) {
            float xs[4] = {xv[j].x, xv[j].y, xv[j].z, xv[j].w};
#pragma unroll
            for (int e = 0; e < 4; ++e) {
                float4 w = wf[j * 4 + e];
                float s = xs[e];
                acc.x = fmaf(s, w.x, acc.x);
                acc.y = fmaf(s, w.y, acc.y);
                acc.z = fmaf(s, w.z, acc.z);
                acc.w = fmaf(s, w.w, acc.w);
            }
        }
#pragma unroll
        for (int m = 1; m < 16; m <<= 1) {
            acc.x += __shfl_xor(acc.x, m, 64);
            acc.y += __shfl_xor(acc.y, m, 64);
            acc.z += __shfl_xor(acc.z, m, 64);
            acc.w += __shfl_xor(acc.w, m, 64);
        }
        if (kg == 0)
            *(float4*)&h1[(size_t)node * HID + cg * 4] = acc;
    }
}

// agg[dst] += w_e * h[src]; 4 lanes per edge, each handling 4 columns.
__global__ __launch_bounds__(256) void scatter_kernel(
    const void* __restrict__ eidx, const float* __restrict__ ew,
    const float* __restrict__ h, float* __restrict__ agg, int nE)
{
    int gid = blockIdx.x * 256 + threadIdx.x;
    int e = gid >> 2;
    if (e >= nE) return;
    int c4 = gid & 3;
    int s, d;
    if (g_idx64) {
        const long long* p = (const long long*)eidx;
        s = (int)p[e];
        d = (int)p[nE + e];
    } else {
        const int* p = (const int*)eidx;
        s = p[e];
        d = p[nE + e];
    }
    if ((unsigned)s >= (unsigned)NN || (unsigned)d >= (unsigned)NN) return;
    float w = ew[e];
    float4 v = ((const float4*)h)[(size_t)s * 4 + c4];
    float* o = agg + (size_t)d * 16 + c4 * 4;
    atomicAdd(o + 0, w * v.x);
    atomicAdd(o + 1, w * v.y);
    atomicAdd(o + 2, w * v.z);
    atomicAdd(o + 3, w * v.w);
}

// h2 = relu(agg1 + b1) @ W2
__global__ __launch_bounds__(256) void transform_kernel(
    const float* __restrict__ agg1, const float* __restrict__ b1,
    const float* __restrict__ W2, float* __restrict__ h2, int nN)
{
    __shared__ float sW2[256];
    __shared__ float sb1[16];
    sW2[threadIdx.x] = W2[threadIdx.x];
    if (threadIdx.x < 16) sb1[threadIdx.x] = b1[threadIdx.x];
    __syncthreads();
    int n = blockIdx.x * 256 + threadIdx.x;
    if (n >= nN) return;
    const float4* r = (const float4*)(agg1 + (size_t)n * 16);
    float v[16];
#pragma unroll
    for (int g = 0; g < 4; ++g) {
        float4 a = r[g];
        v[g * 4 + 0] = fmaxf(a.x + sb1[g * 4 + 0], 0.f);
        v[g * 4 + 1] = fmaxf(a.y + sb1[g * 4 + 1], 0.f);
        v[g * 4 + 2] = fmaxf(a.z + sb1[g * 4 + 2], 0.f);
        v[g * 4 + 3] = fmaxf(a.w + sb1[g * 4 + 3], 0.f);
    }
    float acc[16];
#pragma unroll
    for (int c = 0; c < 16; ++c) acc[c] = 0.f;
#pragma unroll
    for (int k = 0; k < 16; ++k) {
        float s = v[k];
#pragma unroll
        for (int c = 0; c < 16; ++c)
            acc[c] = fmaf(s, sW2[k * 16 + c], acc[c]);
    }
    float4* o = (float4*)(h2 + (size_t)n * 16);
#pragma unroll
    for (int g = 0; g < 4; ++g)
        o[g] = make_float4(acc[g * 4 + 0], acc[g * 4 + 1], acc[g * 4 + 2], acc[g * 4 + 3]);
}

// out = log_softmax(agg2 + b2)
__global__ __launch_bounds__(256) void logsoftmax_kernel(
    const float* __restrict__ agg2, const float* __restrict__ b2,
    float* __restrict__ out, int nN)
{
    __shared__ float sb2[16];
    if (threadIdx.x < 16) sb2[threadIdx.x] = b2[threadIdx.x];
    __syncthreads();
    int n = blockIdx.x * 256 + threadIdx.x;
    if (n >= nN) return;
    const float4* r = (const float4*)(agg2 + (size_t)n * 16);
    float v[16];
#pragma unroll
    for (int g = 0; g < 4; ++g) {
        float4 a = r[g];
        v[g * 4 + 0] = a.x + sb2[g * 4 + 0];
        v[g * 4 + 1] = a.y + sb2[g * 4 + 1];
        v[g * 4 + 2] = a.z + sb2[g * 4 + 2];
        v[g * 4 + 3] = a.w + sb2[g * 4 + 3];
    }
    float m = v[0];
#pragma unroll
    for (int c = 1; c < 16; ++c) m = fmaxf(m, v[c]);
    float s = 0.f;
#pragma unroll
    for (int c = 0; c < 16; ++c) s += expf(v[c] - m);
    float l = m + logf(s);
    float4* o = (float4*)(out + (size_t)n * 16);
#pragma unroll
    for (int g = 0; g < 4; ++g)
        o[g] = make_float4(v[g * 4 + 0] - l, v[g * 4 + 1] - l,
                           v[g * 4 + 2] - l, v[g * 4 + 3] - l);
}

extern "C" void kernel_launch(void* const* d_in, const int* in_sizes, int n_in,
                              void* d_out, int out_size, void* d_ws, size_t ws_size,
                              hipStream_t stream)
{
    const float* x  = (const float*)d_in[0];
    const void*  ei = d_in[1];
    const float* ew = (const float*)d_in[2];
    const float* W1 = (const float*)d_in[3];
    const float* b1 = (const float*)d_in[4];
    const float* W2 = (const float*)d_in[5];
    const float* b2 = (const float*)d_in[6];
    float* out = (float*)d_out;

    const int N = NN;
    const int E = in_sizes[2];          // edge_weight length = n_edges

    float* buf0 = (float*)d_ws;                    // h1, then h2
    float* buf1 = buf0 + (size_t)N * HID;          // agg1, then agg2
    const size_t aggBytes = (size_t)N * HID * sizeof(float);

    hipMemsetAsync(buf1, 0, aggBytes, stream);
    detect_idx_kernel<<<1, 64, 0, stream>>>((const long long*)ei);
    gemm1_kernel<<<1024, 256, 0, stream>>>(x, W1, buf0, N);

    int sblocks = (int)(((long long)E * 4 + 255) / 256);
    scatter_kernel<<<sblocks, 256, 0, stream>>>(ei, ew, buf0, buf1, E);
    transform_kernel<<<(N + 255) / 256, 256, 0, stream>>>(buf1, b1, W2, buf0, N);

    hipMemsetAsync(buf1, 0, aggBytes, stream);
    scatter_kernel<<<sblocks, 256, 0, stream>>>(ei, ew, buf0, buf1, E);
    logsoftmax_kernel<<<(N + 255) / 256, 256, 0, stream>>>(buf1, b2, out, N);
}

// Round 2
// 1087.478 us; speedup vs baseline: 1.5123x; 1.5123x over previous
//
#include <hip/hip_runtime.h>
#include <math.h>

#define NN 100000
#define DF 512
#define HID 16

// Flag: 1 if edge_index is int64-laid-out, 0 if int32.
__device__ int g_idx64;

__global__ void detect_idx_kernel(const long long* __restrict__ idx) {
    int lane = threadIdx.x;  // 64 threads
    int ok = 1;
    for (int i = lane; i < 128; i += 64) {
        long long v = idx[i];
        if (v < 0 || v >= NN) ok = 0;
    }
    unsigned long long m = __ballot(ok);
    if (lane == 0) g_idx64 = (m == ~0ULL);
}

// ---------------- GEMM1: h1 = x @ W1 (wave per node, W1 in registers) ------
__global__ __launch_bounds__(256, 2) void gemm1_kernel(
    const float* __restrict__ x, const float* __restrict__ W1,
    float* __restrict__ h1, int nN)
{
    const int lane = threadIdx.x & 63;
    const int waveId = blockIdx.x * (blockDim.x >> 6) + (threadIdx.x >> 6);
    const int nWaves = gridDim.x * (blockDim.x >> 6);
    const int kg = lane & 15;
    const int cg = lane >> 4;

    float4 wf[32];
#pragma unroll
    for (int j = 0; j < 32; ++j)
        wf[j] = *(const float4*)&W1[(kg * 32 + j) * HID + cg * 4];

    for (int node = waveId; node < nN; node += nWaves) {
        const float4* xr = (const float4*)&x[(size_t)node * DF + kg * 32];
        float4 xv[8];
#pragma unroll
        for (int j = 0; j < 8; ++j) xv[j] = xr[j];

        float4 acc = make_float4(0.f, 0.f, 0.f, 0.f);
#pragma unroll
        for (int j = 0; j < 8; ++j) {
            float xs[4] = {xv[j].x, xv[j].y, xv[j].z, xv[j].w};
#pragma unroll
            for (int e = 0; e < 4; ++e) {
                float4 w = wf[j * 4 + e];
                float s = xs[e];
                acc.x = fmaf(s, w.x, acc.x);
                acc.y = fmaf(s, w.y, acc.y);
                acc.z = fmaf(s, w.z, acc.z);
                acc.w = fmaf(s, w.w, acc.w);
            }
        }
#pragma unroll
        for (int m = 1; m < 16; m <<= 1) {
            acc.x += __shfl_xor(acc.x, m, 64);
            acc.y += __shfl_xor(acc.y, m, 64);
            acc.z += __shfl_xor(acc.z, m, 64);
            acc.w += __shfl_xor(acc.w, m, 64);
        }
        if (kg == 0)
            *(float4*)&h1[(size_t)node * HID + cg * 4] = acc;
    }
}

// ---------------- CSR build ------------------------------------------------
__global__ __launch_bounds__(256) void hist_kernel(
    const void* __restrict__ eidx, int* __restrict__ cnt, int nE)
{
    int e = blockIdx.x * 256 + threadIdx.x;
    if (e >= nE) return;
    int d;
    if (g_idx64) d = (int)((const long long*)eidx)[nE + e];
    else         d = ((const int*)eidx)[nE + e];
    if ((unsigned)d < (unsigned)NN) atomicAdd(&cnt[d], 1);
}

// Single block, 1024 threads: exclusive scan of cnt[0..n) in place, also
// copies result into next[], writes total into cnt[n].
__global__ __launch_bounds__(1024) void scan_kernel(
    int* __restrict__ cnt, int* __restrict__ next, int n)
{
    __shared__ int sums[1024];
    int t = threadIdx.x;
    int chunk = (n + 1023) / 1024;
    int beg = t * chunk;
    int end = min(beg + chunk, n);
    int s = 0;
    for (int i = beg; i < end; ++i) s += cnt[i];
    sums[t] = s;
    __syncthreads();
    for (int off = 1; off < 1024; off <<= 1) {
        int addv = (t >= off) ? sums[t - off] : 0;
        __syncthreads();
        sums[t] += addv;
        __syncthreads();
    }
    int run = sums[t] - s;  // exclusive base of this chunk
    for (int i = beg; i < end; ++i) {
        int c = cnt[i];
        cnt[i] = run;
        next[i] = run;
        run += c;
    }
    if (t == 1023) cnt[n] = run;  // total valid edges
}

__global__ __launch_bounds__(256) void fill_kernel(
    const void* __restrict__ eidx, const float* __restrict__ ew,
    int* __restrict__ next, int2* __restrict__ se, int nE)
{
    int e = blockIdx.x * 256 + threadIdx.x;
    if (e >= nE) return;
    int s, d;
    if (g_idx64) {
        const long long* p = (const long long*)eidx;
        s = (int)p[e];
        d = (int)p[nE + e];
    } else {
        const int* p = (const int*)eidx;
        s = p[e];
        d = p[nE + e];
    }
    if ((unsigned)s >= (unsigned)NN || (unsigned)d >= (unsigned)NN) return;
    int pos = atomicAdd(&next[d], 1);
    se[pos] = make_int2(s, __float_as_int(ew[e]));
}

// ---------------- Aggregation: agg[n] = sum_e w_e * h[src_e] ---------------
// 4 threads per node, each owns one float4 column group. No atomics.
__global__ __launch_bounds__(256) void gather_kernel(
    const int* __restrict__ rowStart, const int2* __restrict__ se,
    const float* __restrict__ h, float* __restrict__ agg, int nN)
{
    int t = blockIdx.x * 256 + threadIdx.x;
    int n = t >> 2;
    if (n >= nN) return;
    int c4 = t & 3;
    int beg = rowStart[n], end = rowStart[n + 1];
    const float4* h4 = (const float4*)h;
    float4 acc = make_float4(0.f, 0.f, 0.f, 0.f);
    for (int p = beg; p < end; ++p) {
        int2 e = se[p];
        float w = __int_as_float(e.y);
        float4 v = h4[(size_t)e.x * 4 + c4];
        acc.x = fmaf(w, v.x, acc.x);
        acc.y = fmaf(w, v.y, acc.y);
        acc.z = fmaf(w, v.z, acc.z);
        acc.w = fmaf(w, v.w, acc.w);
    }
    ((float4*)agg)[(size_t)n * 4 + c4] = acc;
}

// ---------------- Fallback atomic scatter (if ws too small) ----------------
__global__ __launch_bounds__(256) void scatter_kernel(
    const void* __restrict__ eidx, const float* __restrict__ ew,
    const float* __restrict__ h, float* __restrict__ agg, int nE)
{
    int gid = blockIdx.x * 256 + threadIdx.x;
    int e = gid >> 2;
    if (e >= nE) return;
    int c4 = gid & 3;
    int s, d;
    if (g_idx64) {
        const long long* p = (const long long*)eidx;
        s = (int)p[e];
        d = (int)p[nE + e];
    } else {
        const int* p = (const int*)eidx;
        s = p[e];
        d = p[nE + e];
    }
    if ((unsigned)s >= (unsigned)NN || (unsigned)d >= (unsigned)NN) return;
    float w = ew[e];
    float4 v = ((const float4*)h)[(size_t)s * 4 + c4];
    float* o = agg + (size_t)d * 16 + c4 * 4;
    atomicAdd(o + 0, w * v.x);
    atomicAdd(o + 1, w * v.y);
    atomicAdd(o + 2, w * v.z);
    atomicAdd(o + 3, w * v.w);
}

// ---------------- h2 = relu(agg1 + b1) @ W2 --------------------------------
__global__ __launch_bounds__(256) void transform_kernel(
    const float* __restrict__ agg1, const float* __restrict__ b1,
    const float* __restrict__ W2, float* __restrict__ h2, int nN)
{
    __shared__ float sW2[256];
    __shared__ float sb1[16];
    sW2[threadIdx.x] = W2[threadIdx.x];
    if (threadIdx.x < 16) sb1[threadIdx.x] = b1[threadIdx.x];
    __syncthreads();
    int n = blockIdx.x * 256 + threadIdx.x;
    if (n >= nN) return;
    const float4* r = (const float4*)(agg1 + (size_t)n * 16);
    float v[16];
#pragma unroll
    for (int g = 0; g < 4; ++g) {
        float4 a = r[g];
        v[g * 4 + 0] = fmaxf(a.x + sb1[g * 4 + 0], 0.f);
        v[g * 4 + 1] = fmaxf(a.y + sb1[g * 4 + 1], 0.f);
        v[g * 4 + 2] = fmaxf(a.z + sb1[g * 4 + 2], 0.f);
        v[g * 4 + 3] = fmaxf(a.w + sb1[g * 4 + 3], 0.f);
    }
    float acc[16];
#pragma unroll
    for (int c = 0; c < 16; ++c) acc[c] = 0.f;
#pragma unroll
    for (int k = 0; k < 16; ++k) {
        float s = v[k];
#pragma unroll
        for (int c = 0; c < 16; ++c)
            acc[c] = fmaf(s, sW2[k * 16 + c], acc[c]);
    }
    float4* o = (float4*)(h2 + (size_t)n * 16);
#pragma unroll
    for (int g = 0; g < 4; ++g)
        o[g] = make_float4(acc[g * 4 + 0], acc[g * 4 + 1], acc[g * 4 + 2], acc[g * 4 + 3]);
}

// ---------------- out = log_softmax(agg2 + b2) -----------------------------
__global__ __launch_bounds__(256) void logsoftmax_kernel(
    const float* __restrict__ agg2, const float* __restrict__ b2,
    float* __restrict__ out, int nN)
{
    __shared__ float sb2[16];
    if (threadIdx.x < 16) sb2[threadIdx.x] = b2[threadIdx.x];
    __syncthreads();
    int n = blockIdx.x * 256 + threadIdx.x;
    if (n >= nN) return;
    const float4* r = (const float4*)(agg2 + (size_t)n * 16);
    float v[16];
#pragma unroll
    for (int g = 0; g < 4; ++g) {
        float4 a = r[g];
        v[g * 4 + 0] = a.x + sb2[g * 4 + 0];
        v[g * 4 + 1] = a.y + sb2[g * 4 + 1];
        v[g * 4 + 2] = a.z + sb2[g * 4 + 2];
        v[g * 4 + 3] = a.w + sb2[g * 4 + 3];
    }
    float m = v[0];
#pragma unroll
    for (int c = 1; c < 16; ++c) m = fmaxf(m, v[c]);
    float s = 0.f;
#pragma unroll
    for (int c = 0; c < 16; ++c) s += expf(v[c] - m);
    float l = m + logf(s);
    float4* o = (float4*)(out + (size_t)n * 16);
#pragma unroll
    for (int g = 0; g < 4; ++g)
        o[g] = make_float4(v[g * 4 + 0] - l, v[g * 4 + 1] - l,
                           v[g * 4 + 2] - l, v[g * 4 + 3] - l);
}

extern "C" void kernel_launch(void* const* d_in, const int* in_sizes, int n_in,
                              void* d_out, int out_size, void* d_ws, size_t ws_size,
                              hipStream_t stream)
{
    const float* x  = (const float*)d_in[0];
    const void*  ei = d_in[1];
    const float* ew = (const float*)d_in[2];
    const float* W1 = (const float*)d_in[3];
    const float* b1 = (const float*)d_in[4];
    const float* W2 = (const float*)d_in[5];
    const float* b2 = (const float*)d_in[6];
    float* out = (float*)d_out;

    const int N = NN;
    const int E = in_sizes[2];

    const size_t featB = (size_t)N * HID * sizeof(float);          // 6.4 MB
    const size_t rowB  = (((size_t)(N + 1) * 4) + 255) & ~255ULL;  // ~400 KB
    const size_t seB   = (size_t)E * 8;                            // 25.6 MB

    char* w = (char*)d_ws;
    float* buf0 = (float*)w;              w += (featB + 255) & ~255ULL;
    float* buf1 = (float*)w;              w += (featB + 255) & ~255ULL;
    int*   rowStart = (int*)w;            w += rowB;
    int*   nxt = (int*)w;                 w += rowB;
    int2*  se  = (int2*)w;                w += (seB + 255) & ~255ULL;
    const size_t need = (size_t)(w - (char*)d_ws);

    detect_idx_kernel<<<1, 64, 0, stream>>>((const long long*)ei);
    gemm1_kernel<<<1024, 256, 0, stream>>>(x, W1, buf0, N);

    const int eblocks = (E + 255) / 256;
    const int nblocks4 = (N * 4 + 255) / 256;

    if (need <= ws_size) {
        // CSR path: build once, gather twice, no float atomics.
        hipMemsetAsync(rowStart, 0, (size_t)(N + 1) * 4, stream);
        hist_kernel<<<eblocks, 256, 0, stream>>>(ei, rowStart, E);
        scan_kernel<<<1, 1024, 0, stream>>>(rowStart, nxt, N);
        fill_kernel<<<eblocks, 256, 0, stream>>>(ei, ew, nxt, se, E);

        gather_kernel<<<nblocks4, 256, 0, stream>>>(rowStart, se, buf0, buf1, N);
        transform_kernel<<<(N + 255) / 256, 256, 0, stream>>>(buf1, b1, W2, buf0, N);
        gather_kernel<<<nblocks4, 256, 0, stream>>>(rowStart, se, buf0, buf1, N);
        logsoftmax_kernel<<<(N + 255) / 256, 256, 0, stream>>>(buf1, b2, out, N);
    } else {
        // Fallback: atomic scatter.
        const int sblocks = (int)(((long long)E * 4 + 255) / 256);
        hipMemsetAsync(buf1, 0, featB, stream);
        scatter_kernel<<<sblocks, 256, 0, stream>>>(ei, ew, buf0, buf1, E);
        transform_kernel<<<(N + 255) / 256, 256, 0, stream>>>(buf1, b1, W2, buf0, N);
        hipMemsetAsync(buf1, 0, featB, stream);
        scatter_kernel<<<sblocks, 256, 0, stream>>>(ei, ew, buf0, buf1, E);
        logsoftmax_kernel<<<(N + 255) / 256, 256, 0, stream>>>(buf1, b2, out, N);
    }
}

// Round 3
// 887.657 us; speedup vs baseline: 1.8527x; 1.2251x over previous
//
#include <hip/hip_runtime.h>
#include <math.h>

#define NN 100000
#define DF 512
#define HID 16
#define NBUCK 392            // ceil(NN/256) buckets of 256 dst values
#define EPB 4096             // edges per block in bucketA (256 thr x 16)

// Flag: 1 if edge_index is int64-laid-out, 0 if int32.
__device__ int g_idx64;

__global__ void detect_idx_kernel(const long long* __restrict__ idx) {
    int lane = threadIdx.x;  // 64 threads
    int ok = 1;
    for (int i = lane; i < 128; i += 64) {
        long long v = idx[i];
        if (v < 0 || v >= NN) ok = 0;
    }
    unsigned long long m = __ballot(ok);
    if (lane == 0) g_idx64 = (m == ~0ULL);
}

// ---------------- GEMM1: h1 = x @ W1 (wave per node, W1 in registers) ------
__global__ __launch_bounds__(256, 2) void gemm1_kernel(
    const float* __restrict__ x, const float* __restrict__ W1,
    float* __restrict__ h1, int nN)
{
    const int lane = threadIdx.x & 63;
    const int waveId = blockIdx.x * (blockDim.x >> 6) + (threadIdx.x >> 6);
    const int nWaves = gridDim.x * (blockDim.x >> 6);
    const int kg = lane & 15;
    const int cg = lane >> 4;

    float4 wf[32];
#pragma unroll
    for (int j = 0; j < 32; ++j)
        wf[j] = *(const float4*)&W1[(kg * 32 + j) * HID + cg * 4];

    for (int node = waveId; node < nN; node += nWaves) {
        const float4* xr = (const float4*)&x[(size_t)node * DF + kg * 32];
        float4 xv[8];
#pragma unroll
        for (int j = 0; j < 8; ++j) xv[j] = xr[j];

        float4 acc = make_float4(0.f, 0.f, 0.f, 0.f);
#pragma unroll
        for (int j = 0; j < 8; ++j) {
            float xs[4] = {xv[j].x, xv[j].y, xv[j].z, xv[j].w};
#pragma unroll
            for (int e = 0; e < 4; ++e) {
                float4 w = wf[j * 4 + e];
                float s = xs[e];
                acc.x = fmaf(s, w.x, acc.x);
                acc.y = fmaf(s, w.y, acc.y);
                acc.z = fmaf(s, w.z, acc.z);
                acc.w = fmaf(s, w.w, acc.w);
            }
        }
#pragma unroll
        for (int m = 1; m < 16; m <<= 1) {
            acc.x += __shfl_xor(acc.x, m, 64);
            acc.y += __shfl_xor(acc.y, m, 64);
            acc.z += __shfl_xor(acc.z, m, 64);
            acc.w += __shfl_xor(acc.w, m, 64);
        }
        if (kg == 0)
            *(float4*)&h1[(size_t)node * HID + cg * 4] = acc;
    }
}

// ---------------- CSR build ------------------------------------------------
__global__ __launch_bounds__(256) void hist_kernel(
    const void* __restrict__ eidx, int* __restrict__ cnt, int nE)
{
    int e = blockIdx.x * 256 + threadIdx.x;
    if (e >= nE) return;
    int d;
    if (g_idx64) d = (int)((const long long*)eidx)[nE + e];
    else         d = ((const int*)eidx)[nE + e];
    if ((unsigned)d < (unsigned)NN) atomicAdd(&cnt[d], 1);
}

// Single block, 1024 threads: exclusive scan of cnt[0..n) in place; total at cnt[n].
__global__ __launch_bounds__(1024) void scan_kernel(int* __restrict__ cnt, int n)
{
    __shared__ int sums[1024];
    int t = threadIdx.x;
    int chunk = (n + 1023) / 1024;
    int beg = t * chunk;
    int end = min(beg + chunk, n);
    int s = 0;
    for (int i = beg; i < end; ++i) s += cnt[i];
    sums[t] = s;
    __syncthreads();
    for (int off = 1; off < 1024; off <<= 1) {
        int addv = (t >= off) ? sums[t - off] : 0;
        __syncthreads();
        sums[t] += addv;
        __syncthreads();
    }
    int run = sums[t] - s;  // exclusive base of this chunk
    for (int i = beg; i < end; ++i) {
        int c = cnt[i];
        cnt[i] = run;
        run += c;
    }
    if (t == 1023) cnt[n] = run;
}

// nxt[i] = cnt[i]; bucket bases/cursors from rowStart. Grid covers [0, N].
__global__ __launch_bounds__(256) void csr_init_kernel(
    const int* __restrict__ cnt, int* __restrict__ nxt,
    int* __restrict__ bbase, int* __restrict__ cursor, int n)
{
    int i = blockIdx.x * 256 + threadIdx.x;
    if (i > n) return;
    nxt[i] = cnt[i];
    if (i <= NBUCK) {
        int v = i << 8;
        if (v > n) v = n;
        bbase[i] = cnt[v];
        if (i < NBUCK) cursor[i] = cnt[v];
    }
}

// Pass A: coarse bucket sort. Each block stages EPB edges, reserves
// bucket-contiguous runs, writes packed {src | dstlocal<<20, w}.
__global__ __launch_bounds__(256) void bucketA_kernel(
    const void* __restrict__ eidx, const float* __restrict__ ew,
    int* __restrict__ cursor, int2* __restrict__ packed, int nE)
{
    __shared__ int cnt[NBUCK];
    __shared__ int base[NBUCK];
    int t = threadIdx.x;
    for (int i = t; i < NBUCK; i += 256) cnt[i] = 0;
    __syncthreads();

    const int e0 = blockIdx.x * EPB;
    const int i64 = g_idx64;
    int lo[16]; float wv[16]; int bk[16];
#pragma unroll
    for (int i = 0; i < 16; ++i) {
        int e = e0 + t + i * 256;
        bk[i] = -1;
        if (e < nE) {
            int s, d;
            if (i64) {
                const long long* p = (const long long*)eidx;
                s = (int)p[e]; d = (int)p[nE + e];
            } else {
                const int* p = (const int*)eidx;
                s = p[e]; d = p[nE + e];
            }
            if ((unsigned)d < (unsigned)NN) {
                float w = ew[e];
                if ((unsigned)s >= (unsigned)NN) { s = 0; w = 0.f; }
                bk[i] = d >> 8;
                lo[i] = s | ((d & 255) << 20);
                wv[i] = w;
                atomicAdd(&cnt[bk[i]], 1);
            }
        }
    }
    __syncthreads();
    for (int i = t; i < NBUCK; i += 256)
        base[i] = (cnt[i] > 0) ? atomicAdd(&cursor[i], cnt[i]) : 0;
    __syncthreads();
    for (int i = t; i < NBUCK; i += 256) cnt[i] = 0;
    __syncthreads();
#pragma unroll
    for (int i = 0; i < 16; ++i) {
        if (bk[i] >= 0) {
            int r = atomicAdd(&cnt[bk[i]], 1);
            packed[base[bk[i]] + r] = make_int2(lo[i], __float_as_int(wv[i]));
        }
    }
}

// Pass B: one block per bucket; final CSR placement. All writes land in this
// bucket's contiguous se region (single CU -> L2 write-combined).
__global__ __launch_bounds__(256) void bucketB_kernel(
    const int2* __restrict__ packed, const int* __restrict__ bbase,
    int* __restrict__ nxt, int2* __restrict__ se)
{
    int b = blockIdx.x;
    int beg = bbase[b], end = bbase[b + 1];
    for (int p = beg + threadIdx.x; p < end; p += 256) {
        int2 e = packed[p];
        int src = e.x & 0xFFFFF;
        int dst = (b << 8) + ((e.x >> 20) & 255);
        int pos = atomicAdd(&nxt[dst], 1);
        se[pos] = make_int2(src, e.y);
    }
}

// Fallback direct fill (old path).
__global__ __launch_bounds__(256) void fill_kernel(
    const void* __restrict__ eidx, const float* __restrict__ ew,
    int* __restrict__ next, int2* __restrict__ se, int nE)
{
    int e = blockIdx.x * 256 + threadIdx.x;
    if (e >= nE) return;
    int s, d;
    if (g_idx64) {
        const long long* p = (const long long*)eidx;
        s = (int)p[e]; d = (int)p[nE + e];
    } else {
        const int* p = (const int*)eidx;
        s = p[e]; d = p[nE + e];
    }
    if ((unsigned)d >= (unsigned)NN) return;
    float w = ew[e];
    if ((unsigned)s >= (unsigned)NN) { s = 0; w = 0.f; }
    int pos = atomicAdd(&next[d], 1);
    se[pos] = make_int2(s, __float_as_int(w));
}

// ---------------- Aggregation: agg[n] = sum_e w_e * h[src_e] ---------------
__global__ __launch_bounds__(256) void gather_kernel(
    const int* __restrict__ rowStart, const int2* __restrict__ se,
    const float* __restrict__ h, float* __restrict__ agg, int nN)
{
    int t = blockIdx.x * 256 + threadIdx.x;
    int n = t >> 2;
    if (n >= nN) return;
    int c4 = t & 3;
    int beg = rowStart[n], end = rowStart[n + 1];
    const float4* h4 = (const float4*)h;
    float4 acc = make_float4(0.f, 0.f, 0.f, 0.f);
    for (int p = beg; p < end; ++p) {
        int2 e = se[p];
        float w = __int_as_float(e.y);
        float4 v = h4[(size_t)e.x * 4 + c4];
        acc.x = fmaf(w, v.x, acc.x);
        acc.y = fmaf(w, v.y, acc.y);
        acc.z = fmaf(w, v.z, acc.z);
        acc.w = fmaf(w, v.w, acc.w);
    }
    ((float4*)agg)[(size_t)n * 4 + c4] = acc;
}

// ---------------- Fallback atomic scatter ----------------------------------
__global__ __launch_bounds__(256) void scatter_kernel(
    const void* __restrict__ eidx, const float* __restrict__ ew,
    const float* __restrict__ h, float* __restrict__ agg, int nE)
{
    int gid = blockIdx.x * 256 + threadIdx.x;
    int e = gid >> 2;
    if (e >= nE) return;
    int c4 = gid & 3;
    int s, d;
    if (g_idx64) {
        const long long* p = (const long long*)eidx;
        s = (int)p[e]; d = (int)p[nE + e];
    } else {
        const int* p = (const int*)eidx;
        s = p[e]; d = p[nE + e];
    }
    if ((unsigned)s >= (unsigned)NN || (unsigned)d >= (unsigned)NN) return;
    float w = ew[e];
    float4 v = ((const float4*)h)[(size_t)s * 4 + c4];
    float* o = agg + (size_t)d * 16 + c4 * 4;
    atomicAdd(o + 0, w * v.x);
    atomicAdd(o + 1, w * v.y);
    atomicAdd(o + 2, w * v.z);
    atomicAdd(o + 3, w * v.w);
}

// ---------------- h2 = relu(agg1 + b1) @ W2 --------------------------------
__global__ __launch_bounds__(256) void transform_kernel(
    const float* __restrict__ agg1, const float* __restrict__ b1,
    const float* __restrict__ W2, float* __restrict__ h2, int nN)
{
    __shared__ float sW2[256];
    __shared__ float sb1[16];
    sW2[threadIdx.x] = W2[threadIdx.x];
    if (threadIdx.x < 16) sb1[threadIdx.x] = b1[threadIdx.x];
    __syncthreads();
    int n = blockIdx.x * 256 + threadIdx.x;
    if (n >= nN) return;
    const float4* r = (const float4*)(agg1 + (size_t)n * 16);
    float v[16];
#pragma unroll
    for (int g = 0; g < 4; ++g) {
        float4 a = r[g];
        v[g * 4 + 0] = fmaxf(a.x + sb1[g * 4 + 0], 0.f);
        v[g * 4 + 1] = fmaxf(a.y + sb1[g * 4 + 1], 0.f);
        v[g * 4 + 2] = fmaxf(a.z + sb1[g * 4 + 2], 0.f);
        v[g * 4 + 3] = fmaxf(a.w + sb1[g * 4 + 3], 0.f);
    }
    float acc[16];
#pragma unroll
    for (int c = 0; c < 16; ++c) acc[c] = 0.f;
#pragma unroll
    for (int k = 0; k < 16; ++k) {
        float s = v[k];
#pragma unroll
        for (int c = 0; c < 16; ++c)
            acc[c] = fmaf(s, sW2[k * 16 + c], acc[c]);
    }
    float4* o = (float4*)(h2 + (size_t)n * 16);
#pragma unroll
    for (int g = 0; g < 4; ++g)
        o[g] = make_float4(acc[g * 4 + 0], acc[g * 4 + 1], acc[g * 4 + 2], acc[g * 4 + 3]);
}

// ---------------- out = log_softmax(agg2 + b2) -----------------------------
__global__ __launch_bounds__(256) void logsoftmax_kernel(
    const float* __restrict__ agg2, const float* __restrict__ b2,
    float* __restrict__ out, int nN)
{
    __shared__ float sb2[16];
    if (threadIdx.x < 16) sb2[threadIdx.x] = b2[threadIdx.x];
    __syncthreads();
    int n = blockIdx.x * 256 + threadIdx.x;
    if (n >= nN) return;
    const float4* r = (const float4*)(agg2 + (size_t)n * 16);
    float v[16];
#pragma unroll
    for (int g = 0; g < 4; ++g) {
        float4 a = r[g];
        v[g * 4 + 0] = a.x + sb2[g * 4 + 0];
        v[g * 4 + 1] = a.y + sb2[g * 4 + 1];
        v[g * 4 + 2] = a.z + sb2[g * 4 + 2];
        v[g * 4 + 3] = a.w + sb2[g * 4 + 3];
    }
    float m = v[0];
#pragma unroll
    for (int c = 1; c < 16; ++c) m = fmaxf(m, v[c]);
    float s = 0.f;
#pragma unroll
    for (int c = 0; c < 16; ++c) s += expf(v[c] - m);
    float l = m + logf(s);
    float4* o = (float4*)(out + (size_t)n * 16);
#pragma unroll
    for (int g = 0; g < 4; ++g)
        o[g] = make_float4(v[g * 4 + 0] - l, v[g * 4 + 1] - l,
                           v[g * 4 + 2] - l, v[g * 4 + 3] - l);
}

extern "C" void kernel_launch(void* const* d_in, const int* in_sizes, int n_in,
                              void* d_out, int out_size, void* d_ws, size_t ws_size,
                              hipStream_t stream)
{
    const float* x  = (const float*)d_in[0];
    const void*  ei = d_in[1];
    const float* ew = (const float*)d_in[2];
    const float* W1 = (const float*)d_in[3];
    const float* b1 = (const float*)d_in[4];
    const float* W2 = (const float*)d_in[5];
    const float* b2 = (const float*)d_in[6];
    float* out = (float*)d_out;

    const int N = NN;
    const int E = in_sizes[2];

    const size_t featB = (size_t)N * HID * sizeof(float);           // 6.4 MB
    const size_t rowB  = (((size_t)(N + 1) * 4) + 255) & ~255ULL;
    const size_t bkB   = (((size_t)(NBUCK + 1) * 4) + 255) & ~255ULL;
    const size_t seB   = ((size_t)E * 8 + 255) & ~255ULL;           // 25.6 MB

    char* w = (char*)d_ws;
    float* buf0 = (float*)w;      w += (featB + 255) & ~255ULL;
    float* buf1 = (float*)w;      w += (featB + 255) & ~255ULL;
    int*   rowStart = (int*)w;    w += rowB;
    int*   nxt = (int*)w;         w += rowB;
    int*   bbase = (int*)w;       w += bkB;
    int*   cursor = (int*)w;      w += bkB;
    int2*  se = (int2*)w;         w += seB;
    const size_t needCSR = (size_t)(w - (char*)d_ws);
    int2*  packed = (int2*)w;     w += seB;
    const size_t needFull = (size_t)(w - (char*)d_ws);

    detect_idx_kernel<<<1, 64, 0, stream>>>((const long long*)ei);
    gemm1_kernel<<<1024, 256, 0, stream>>>(x, W1, buf0, N);

    const int eblocks = (E + 255) / 256;
    const int nblocks4 = (N * 4 + 255) / 256;

    if (needFull <= ws_size) {
        // Bucketed CSR build: localized writes, no line ping-pong.
        hipMemsetAsync(rowStart, 0, (size_t)(N + 1) * 4, stream);
        hist_kernel<<<eblocks, 256, 0, stream>>>(ei, rowStart, E);
        scan_kernel<<<1, 1024, 0, stream>>>(rowStart, N);
        csr_init_kernel<<<(N + 256) / 256, 256, 0, stream>>>(rowStart, nxt, bbase, cursor, N);
        bucketA_kernel<<<(E + EPB - 1) / EPB, 256, 0, stream>>>(ei, ew, cursor, packed, E);
        bucketB_kernel<<<NBUCK, 256, 0, stream>>>(packed, bbase, nxt, se);

        gather_kernel<<<nblocks4, 256, 0, stream>>>(rowStart, se, buf0, buf1, N);
        transform_kernel<<<(N + 255) / 256, 256, 0, stream>>>(buf1, b1, W2, buf0, N);
        gather_kernel<<<nblocks4, 256, 0, stream>>>(rowStart, se, buf0, buf1, N);
        logsoftmax_kernel<<<(N + 255) / 256, 256, 0, stream>>>(buf1, b2, out, N);
    } else if (needCSR <= ws_size) {
        // Direct-fill CSR path.
        hipMemsetAsync(rowStart, 0, (size_t)(N + 1) * 4, stream);
        hist_kernel<<<eblocks, 256, 0, stream>>>(ei, rowStart, E);
        scan_kernel<<<1, 1024, 0, stream>>>(rowStart, N);
        csr_init_kernel<<<(N + 256) / 256, 256, 0, stream>>>(rowStart, nxt, bbase, cursor, N);
        fill_kernel<<<eblocks, 256, 0, stream>>>(ei, ew, nxt, se, E);

        gather_kernel<<<nblocks4, 256, 0, stream>>>(rowStart, se, buf0, buf1, N);
        transform_kernel<<<(N + 255) / 256, 256, 0, stream>>>(buf1, b1, W2, buf0, N);
        gather_kernel<<<nblocks4, 256, 0, stream>>>(rowStart, se, buf0, buf1, N);
        logsoftmax_kernel<<<(N + 255) / 256, 256, 0, stream>>>(buf1, b2, out, N);
    } else {
        // Atomic fallback.
        const int sblocks = (int)(((long long)E * 4 + 255) / 256);
        hipMemsetAsync(buf1, 0, featB, stream);
        scatter_kernel<<<sblocks, 256, 0, stream>>>(ei, ew, buf0, buf1, E);
        transform_kernel<<<(N + 255) / 256, 256, 0, stream>>>(buf1, b1, W2, buf0, N);
        hipMemsetAsync(buf1, 0, featB, stream);
        scatter_kernel<<<sblocks, 256, 0, stream>>>(ei, ew, buf0, buf1, E);
        logsoftmax_kernel<<<(N + 255) / 256, 256, 0, stream>>>(buf1, b2, out, N);
    }
}

// Round 4
// 744.893 us; speedup vs baseline: 2.2078x; 1.1917x over previous
//
#include <hip/hip_runtime.h>
#include <math.h>

#define NN 100000
#define DF 512
#define HID 16
#define NBUCK 392            // ceil(NN/256)+1 buckets of 256 dst values
#define EPB 4096             // edges per block in bucketA (256 thr x 16)
#define SCHUNK 4096          // elements per block in hierarchical scan
#define SBLOCKS ((NN + SCHUNK - 1) / SCHUNK)   // 25

// Flag: 1 if edge_index is int64-laid-out, 0 if int32.
__device__ int g_idx64;

__global__ void detect_idx_kernel(const long long* __restrict__ idx) {
    int lane = threadIdx.x;  // 64 threads
    int ok = 1;
    for (int i = lane; i < 128; i += 64) {
        long long v = idx[i];
        if (v < 0 || v >= NN) ok = 0;
    }
    unsigned long long m = __ballot(ok);
    if (lane == 0) g_idx64 = (m == ~0ULL);
}

// ---------------- GEMM1: h1 = x @ W1 (wave per node, W1 in registers) ------
__global__ __launch_bounds__(256, 2) void gemm1_kernel(
    const float* __restrict__ x, const float* __restrict__ W1,
    float* __restrict__ h1, int nN)
{
    const int lane = threadIdx.x & 63;
    const int waveId = blockIdx.x * (blockDim.x >> 6) + (threadIdx.x >> 6);
    const int nWaves = gridDim.x * (blockDim.x >> 6);
    const int kg = lane & 15;
    const int cg = lane >> 4;

    float4 wf[32];
#pragma unroll
    for (int j = 0; j < 32; ++j)
        wf[j] = *(const float4*)&W1[(kg * 32 + j) * HID + cg * 4];

    for (int node = waveId; node < nN; node += nWaves) {
        const float4* xr = (const float4*)&x[(size_t)node * DF + kg * 32];
        float4 xv[8];
#pragma unroll
        for (int j = 0; j < 8; ++j) xv[j] = xr[j];

        float4 acc = make_float4(0.f, 0.f, 0.f, 0.f);
#pragma unroll
        for (int j = 0; j < 8; ++j) {
            float xs[4] = {xv[j].x, xv[j].y, xv[j].z, xv[j].w};
#pragma unroll
            for (int e = 0; e < 4; ++e) {
                float4 w = wf[j * 4 + e];
                float s = xs[e];
                acc.x = fmaf(s, w.x, acc.x);
                acc.y = fmaf(s, w.y, acc.y);
                acc.z = fmaf(s, w.z, acc.z);
                acc.w = fmaf(s, w.w, acc.w);
            }
        }
#pragma unroll
        for (int m = 1; m < 16; m <<= 1) {
            acc.x += __shfl_xor(acc.x, m, 64);
            acc.y += __shfl_xor(acc.y, m, 64);
            acc.z += __shfl_xor(acc.z, m, 64);
            acc.w += __shfl_xor(acc.w, m, 64);
        }
        if (kg == 0)
            *(float4*)&h1[(size_t)node * HID + cg * 4] = acc;
    }
}

// ---------------- CSR build ------------------------------------------------
__global__ __launch_bounds__(256) void hist_kernel(
    const void* __restrict__ eidx, int* __restrict__ cnt, int nE)
{
    int e = blockIdx.x * 256 + threadIdx.x;
    if (e >= nE) return;
    int d;
    if (g_idx64) d = (int)((const long long*)eidx)[nE + e];
    else         d = ((const int*)eidx)[nE + e];
    if ((unsigned)d < (unsigned)NN) atomicAdd(&cnt[d], 1);
}

// Hierarchical scan, phase A: per-block partial sums of cnt chunks.
__global__ __launch_bounds__(256) void scanA_kernel(
    const int* __restrict__ cnt, int* __restrict__ bsum, int n)
{
    __shared__ int wsum[4];
    int t = threadIdx.x;
    int base = blockIdx.x * SCHUNK;
    int s = 0;
    for (int i = t; i < SCHUNK; i += 256) {
        int idx = base + i;
        if (idx < n) s += cnt[idx];
    }
#pragma unroll
    for (int m = 1; m < 64; m <<= 1) s += __shfl_xor(s, m, 64);
    if ((t & 63) == 0) wsum[t >> 6] = s;
    __syncthreads();
    if (t == 0) bsum[blockIdx.x] = wsum[0] + wsum[1] + wsum[2] + wsum[3];
}

// Phase B: one wave scans block sums -> exclusive bases; grand total -> cnt[n].
__global__ void scanB_kernel(int* __restrict__ bsum, int* __restrict__ cnt,
                             int n, int nb)
{
    int t = threadIdx.x;  // 64 threads
    int v = (t < nb) ? bsum[t] : 0;
    int incl = v;
#pragma unroll
    for (int off = 1; off < 64; off <<= 1) {
        int u = __shfl_up(incl, off, 64);
        if (t >= off) incl += u;
    }
    if (t < nb) bsum[t] = incl - v;   // exclusive base
    if (t == 63) cnt[n] = incl;       // grand total (nb <= 64)
}

// Phase C: each block rescans its chunk writing the exclusive prefix in place.
__global__ __launch_bounds__(256) void scanC_kernel(
    int* __restrict__ cnt, const int* __restrict__ bsum, int n)
{
    __shared__ int tsum[256];
    int t = threadIdx.x;
    int base = blockIdx.x * SCHUNK + t * 16;
    int local[16];
#pragma unroll
    for (int i = 0; i < 16; ++i) {
        int idx = base + i;
        local[i] = (idx < n) ? cnt[idx] : 0;
    }
    int s = 0;
#pragma unroll
    for (int i = 0; i < 16; ++i) { int c = local[i]; local[i] = s; s += c; }
    tsum[t] = s;
    __syncthreads();
    for (int off = 1; off < 256; off <<= 1) {
        int addv = (t >= off) ? tsum[t - off] : 0;
        __syncthreads();
        tsum[t] += addv;
        __syncthreads();
    }
    int off0 = bsum[blockIdx.x] + (tsum[t] - s);
#pragma unroll
    for (int i = 0; i < 16; ++i) {
        int idx = base + i;
        if (idx < n) cnt[idx] = off0 + local[i];
    }
}

// nxt[i] = cnt[i]; bucket bases/cursors from rowStart. Grid covers [0, N].
__global__ __launch_bounds__(256) void csr_init_kernel(
    const int* __restrict__ cnt, int* __restrict__ nxt,
    int* __restrict__ bbase, int* __restrict__ cursor, int n)
{
    int i = blockIdx.x * 256 + threadIdx.x;
    if (i > n) return;
    nxt[i] = cnt[i];
    if (i <= NBUCK) {
        int v = i << 8;
        if (v > n) v = n;
        bbase[i] = cnt[v];
        if (i < NBUCK) cursor[i] = cnt[v];
    }
}

// Pass A: coarse bucket sort. Each block stages EPB edges, reserves
// bucket-contiguous runs, writes packed {src | dstlocal<<20, w}.
__global__ __launch_bounds__(256) void bucketA_kernel(
    const void* __restrict__ eidx, const float* __restrict__ ew,
    int* __restrict__ cursor, int2* __restrict__ packed, int nE)
{
    __shared__ int cnt[NBUCK];
    __shared__ int base[NBUCK];
    int t = threadIdx.x;
    for (int i = t; i < NBUCK; i += 256) cnt[i] = 0;
    __syncthreads();

    const int e0 = blockIdx.x * EPB;
    const int i64 = g_idx64;
    int lo[16]; float wv[16]; int bk[16];
#pragma unroll
    for (int i = 0; i < 16; ++i) {
        int e = e0 + t + i * 256;
        bk[i] = -1;
        if (e < nE) {
            int s, d;
            if (i64) {
                const long long* p = (const long long*)eidx;
                s = (int)p[e]; d = (int)p[nE + e];
            } else {
                const int* p = (const int*)eidx;
                s = p[e]; d = p[nE + e];
            }
            if ((unsigned)d < (unsigned)NN) {
                float w = ew[e];
                if ((unsigned)s >= (unsigned)NN) { s = 0; w = 0.f; }
                bk[i] = d >> 8;
                lo[i] = s | ((d & 255) << 20);
                wv[i] = w;
                atomicAdd(&cnt[bk[i]], 1);
            }
        }
    }
    __syncthreads();
    for (int i = t; i < NBUCK; i += 256)
        base[i] = (cnt[i] > 0) ? atomicAdd(&cursor[i], cnt[i]) : 0;
    __syncthreads();
    for (int i = t; i < NBUCK; i += 256) cnt[i] = 0;
    __syncthreads();
#pragma unroll
    for (int i = 0; i < 16; ++i) {
        if (bk[i] >= 0) {
            int r = atomicAdd(&cnt[bk[i]], 1);
            packed[base[bk[i]] + r] = make_int2(lo[i], __float_as_int(wv[i]));
        }
    }
}

// Pass B: one block per bucket; final CSR placement.
__global__ __launch_bounds__(256) void bucketB_kernel(
    const int2* __restrict__ packed, const int* __restrict__ bbase,
    int* __restrict__ nxt, int2* __restrict__ se)
{
    int b = blockIdx.x;
    int beg = bbase[b], end = bbase[b + 1];
    for (int p = beg + threadIdx.x; p < end; p += 256) {
        int2 e = packed[p];
        int src = e.x & 0xFFFFF;
        int dst = (b << 8) + ((e.x >> 20) & 255);
        int pos = atomicAdd(&nxt[dst], 1);
        se[pos] = make_int2(src, e.y);
    }
}

// ---------------- Aggregation: agg[n] = sum_e w_e * h[src_e] ---------------
__global__ __launch_bounds__(256) void gather_kernel(
    const int* __restrict__ rowStart, const int2* __restrict__ se,
    const float* __restrict__ h, float* __restrict__ agg, int nN)
{
    int t = blockIdx.x * 256 + threadIdx.x;
    int n = t >> 2;
    if (n >= nN) return;
    int c4 = t & 3;
    int beg = rowStart[n], end = rowStart[n + 1];
    const float4* h4 = (const float4*)h;
    float4 acc = make_float4(0.f, 0.f, 0.f, 0.f);
    for (int p = beg; p < end; ++p) {
        int2 e = se[p];
        float w = __int_as_float(e.y);
        float4 v = h4[(size_t)e.x * 4 + c4];
        acc.x = fmaf(w, v.x, acc.x);
        acc.y = fmaf(w, v.y, acc.y);
        acc.z = fmaf(w, v.z, acc.z);
        acc.w = fmaf(w, v.w, acc.w);
    }
    ((float4*)agg)[(size_t)n * 4 + c4] = acc;
}

// ---------------- h2 = relu(agg1 + b1) @ W2 --------------------------------
__global__ __launch_bounds__(256) void transform_kernel(
    const float* __restrict__ agg1, const float* __restrict__ b1,
    const float* __restrict__ W2, float* __restrict__ h2, int nN)
{
    __shared__ float sW2[256];
    __shared__ float sb1[16];
    sW2[threadIdx.x] = W2[threadIdx.x];
    if (threadIdx.x < 16) sb1[threadIdx.x] = b1[threadIdx.x];
    __syncthreads();
    int n = blockIdx.x * 256 + threadIdx.x;
    if (n >= nN) return;
    const float4* r = (const float4*)(agg1 + (size_t)n * 16);
    float v[16];
#pragma unroll
    for (int g = 0; g < 4; ++g) {
        float4 a = r[g];
        v[g * 4 + 0] = fmaxf(a.x + sb1[g * 4 + 0], 0.f);
        v[g * 4 + 1] = fmaxf(a.y + sb1[g * 4 + 1], 0.f);
        v[g * 4 + 2] = fmaxf(a.z + sb1[g * 4 + 2], 0.f);
        v[g * 4 + 3] = fmaxf(a.w + sb1[g * 4 + 3], 0.f);
    }
    float acc[16];
#pragma unroll
    for (int c = 0; c < 16; ++c) acc[c] = 0.f;
#pragma unroll
    for (int k = 0; k < 16; ++k) {
        float s = v[k];
#pragma unroll
        for (int c = 0; c < 16; ++c)
            acc[c] = fmaf(s, sW2[k * 16 + c], acc[c]);
    }
    float4* o = (float4*)(h2 + (size_t)n * 16);
#pragma unroll
    for (int g = 0; g < 4; ++g)
        o[g] = make_float4(acc[g * 4 + 0], acc[g * 4 + 1], acc[g * 4 + 2], acc[g * 4 + 3]);
}

// ---------------- out = log_softmax(agg2 + b2) -----------------------------
__global__ __launch_bounds__(256) void logsoftmax_kernel(
    const float* __restrict__ agg2, const float* __restrict__ b2,
    float* __restrict__ out, int nN)
{
    __shared__ float sb2[16];
    if (threadIdx.x < 16) sb2[threadIdx.x] = b2[threadIdx.x];
    __syncthreads();
    int n = blockIdx.x * 256 + threadIdx.x;
    if (n >= nN) return;
    const float4* r = (const float4*)(agg2 + (size_t)n * 16);
    float v[16];
#pragma unroll
    for (int g = 0; g < 4; ++g) {
        float4 a = r[g];
        v[g * 4 + 0] = a.x + sb2[g * 4 + 0];
        v[g * 4 + 1] = a.y + sb2[g * 4 + 1];
        v[g * 4 + 2] = a.z + sb2[g * 4 + 2];
        v[g * 4 + 3] = a.w + sb2[g * 4 + 3];
    }
    float m = v[0];
#pragma unroll
    for (int c = 1; c < 16; ++c) m = fmaxf(m, v[c]);
    float s = 0.f;
#pragma unroll
    for (int c = 0; c < 16; ++c) s += expf(v[c] - m);
    float l = m + logf(s);
    float4* o = (float4*)(out + (size_t)n * 16);
#pragma unroll
    for (int g = 0; g < 4; ++g)
        o[g] = make_float4(v[g * 4 + 0] - l, v[g * 4 + 1] - l,
                           v[g * 4 + 2] - l, v[g * 4 + 3] - l);
}

extern "C" void kernel_launch(void* const* d_in, const int* in_sizes, int n_in,
                              void* d_out, int out_size, void* d_ws, size_t ws_size,
                              hipStream_t stream)
{
    const float* x  = (const float*)d_in[0];
    const void*  ei = d_in[1];
    const float* ew = (const float*)d_in[2];
    const float* W1 = (const float*)d_in[3];
    const float* b1 = (const float*)d_in[4];
    const float* W2 = (const float*)d_in[5];
    const float* b2 = (const float*)d_in[6];
    float* out = (float*)d_out;

    const int N = NN;
    const int E = in_sizes[2];

    const size_t featB = (size_t)N * HID * sizeof(float);           // 6.4 MB
    const size_t rowB  = (((size_t)(N + 1) * 4) + 255) & ~255ULL;
    const size_t bkB   = (((size_t)(NBUCK + 1) * 4) + 255) & ~255ULL;
    const size_t seB   = ((size_t)E * 8 + 255) & ~255ULL;           // 25.6 MB

    char* w = (char*)d_ws;
    float* buf0 = (float*)w;      w += (featB + 255) & ~255ULL;
    float* buf1 = (float*)w;      w += (featB + 255) & ~255ULL;
    int*   rowStart = (int*)w;    w += rowB;
    int*   nxt = (int*)w;         w += rowB;
    int*   bbase = (int*)w;       w += bkB;
    int*   cursor = (int*)w;      w += bkB;
    int*   bsum = (int*)w;        w += 256;
    int2*  se = (int2*)w;         w += seB;
    int2*  packed = (int2*)w;     w += seB;

    detect_idx_kernel<<<1, 64, 0, stream>>>((const long long*)ei);
    gemm1_kernel<<<1024, 256, 0, stream>>>(x, W1, buf0, N);

    const int eblocks = (E + 255) / 256;
    const int nblocks4 = (N * 4 + 255) / 256;

    // Bucketed CSR build with hierarchical scan.
    hipMemsetAsync(rowStart, 0, (size_t)(N + 1) * 4, stream);
    hist_kernel<<<eblocks, 256, 0, stream>>>(ei, rowStart, E);
    scanA_kernel<<<SBLOCKS, 256, 0, stream>>>(rowStart, bsum, N);
    scanB_kernel<<<1, 64, 0, stream>>>(bsum, rowStart, N, SBLOCKS);
    scanC_kernel<<<SBLOCKS, 256, 0, stream>>>(rowStart, bsum, N);
    csr_init_kernel<<<(N + 256) / 256, 256, 0, stream>>>(rowStart, nxt, bbase, cursor, N);
    bucketA_kernel<<<(E + EPB - 1) / EPB, 256, 0, stream>>>(ei, ew, cursor, packed, E);
    bucketB_kernel<<<NBUCK, 256, 0, stream>>>(packed, bbase, nxt, se);

    gather_kernel<<<nblocks4, 256, 0, stream>>>(rowStart, se, buf0, buf1, N);
    transform_kernel<<<(N + 255) / 256, 256, 0, stream>>>(buf1, b1, W2, buf0, N);
    gather_kernel<<<nblocks4, 256, 0, stream>>>(rowStart, se, buf0, buf1, N);
    logsoftmax_kernel<<<(N + 255) / 256, 256, 0, stream>>>(buf1, b2, out, N);
}

// Round 5
// 713.260 us; speedup vs baseline: 2.3057x; 1.0443x over previous
//
#include <hip/hip_runtime.h>
#include <math.h>

#define NN 100000
#define DF 512
#define HID 16
#define NBUCK 392            // ceil(NN/256)+1 buckets of 256 dst values
#define EPB 4096             // edges per block in bucketA (256 thr x 16)
#define SCHUNK 4096          // elements per block in hierarchical scan
#define SBLOCKS ((NN + SCHUNK - 1) / SCHUNK)   // 25

// Flag: 1 if edge_index is int64-laid-out, 0 if int32.
__device__ int g_idx64;

__global__ void detect_idx_kernel(const long long* __restrict__ idx) {
    int lane = threadIdx.x;  // 64 threads
    int ok = 1;
    for (int i = lane; i < 128; i += 64) {
        long long v = idx[i];
        if (v < 0 || v >= NN) ok = 0;
    }
    unsigned long long m = __ballot(ok);
    if (lane == 0) g_idx64 = (m == ~0ULL);
}

// ---------------- GEMM1: h1 = x @ W1 -------------------------------------
// One thread per node (row-per-thread GEMV). W1 accessed with wave-uniform
// indices -> scalar s_load through K$, zero VALU/VGPR cost. x row streamed
// as 128 float4 loads; each 128B line is fully consumed by its lane across
// 8 consecutive loads, so HBM traffic = exactly |x|. 16 f32 accumulators,
// no cross-lane reduction.
__global__ __launch_bounds__(64) void gemm1_kernel(
    const float* __restrict__ x, const float* __restrict__ W1,
    float* __restrict__ h1, int nN)
{
    int node = blockIdx.x * 64 + threadIdx.x;
    if (node >= nN) return;
    const float4* xr = (const float4*)(x + (size_t)node * DF);

    float acc[16];
#pragma unroll
    for (int c = 0; c < 16; ++c) acc[c] = 0.f;

#pragma unroll 4
    for (int kq = 0; kq < DF / 4; ++kq) {   // 128 iterations, 4 ks each
        float4 xv = xr[kq];
        const float* wrow = W1 + kq * 4 * HID;  // wave-uniform address
        float xs[4] = {xv.x, xv.y, xv.z, xv.w};
#pragma unroll
        for (int j = 0; j < 4; ++j) {
            float s = xs[j];
#pragma unroll
            for (int c = 0; c < 16; ++c)
                acc[c] = fmaf(s, wrow[j * 16 + c], acc[c]);
        }
    }

    float4* o = (float4*)(h1 + (size_t)node * HID);
#pragma unroll
    for (int g = 0; g < 4; ++g)
        o[g] = make_float4(acc[g * 4 + 0], acc[g * 4 + 1],
                           acc[g * 4 + 2], acc[g * 4 + 3]);
}

// ---------------- CSR build ------------------------------------------------
__global__ __launch_bounds__(256) void hist_kernel(
    const void* __restrict__ eidx, int* __restrict__ cnt, int nE)
{
    int e = blockIdx.x * 256 + threadIdx.x;
    if (e >= nE) return;
    int d;
    if (g_idx64) d = (int)((const long long*)eidx)[nE + e];
    else         d = ((const int*)eidx)[nE + e];
    if ((unsigned)d < (unsigned)NN) atomicAdd(&cnt[d], 1);
}

// Hierarchical scan, phase A: per-block partial sums of cnt chunks.
__global__ __launch_bounds__(256) void scanA_kernel(
    const int* __restrict__ cnt, int* __restrict__ bsum, int n)
{
    __shared__ int wsum[4];
    int t = threadIdx.x;
    int base = blockIdx.x * SCHUNK;
    int s = 0;
    for (int i = t; i < SCHUNK; i += 256) {
        int idx = base + i;
        if (idx < n) s += cnt[idx];
    }
#pragma unroll
    for (int m = 1; m < 64; m <<= 1) s += __shfl_xor(s, m, 64);
    if ((t & 63) == 0) wsum[t >> 6] = s;
    __syncthreads();
    if (t == 0) bsum[blockIdx.x] = wsum[0] + wsum[1] + wsum[2] + wsum[3];
}

// Phase B: one wave scans block sums -> exclusive bases; grand total -> cnt[n].
__global__ void scanB_kernel(int* __restrict__ bsum, int* __restrict__ cnt,
                             int n, int nb)
{
    int t = threadIdx.x;  // 64 threads
    int v = (t < nb) ? bsum[t] : 0;
    int incl = v;
#pragma unroll
    for (int off = 1; off < 64; off <<= 1) {
        int u = __shfl_up(incl, off, 64);
        if (t >= off) incl += u;
    }
    if (t < nb) bsum[t] = incl - v;   // exclusive base
    if (t == 63) cnt[n] = incl;       // grand total (nb <= 64)
}

// Phase C: each block rescans its chunk writing the exclusive prefix in place.
__global__ __launch_bounds__(256) void scanC_kernel(
    int* __restrict__ cnt, const int* __restrict__ bsum, int n)
{
    __shared__ int tsum[256];
    int t = threadIdx.x;
    int base = blockIdx.x * SCHUNK + t * 16;
    int local[16];
#pragma unroll
    for (int i = 0; i < 16; ++i) {
        int idx = base + i;
        local[i] = (idx < n) ? cnt[idx] : 0;
    }
    int s = 0;
#pragma unroll
    for (int i = 0; i < 16; ++i) { int c = local[i]; local[i] = s; s += c; }
    tsum[t] = s;
    __syncthreads();
    for (int off = 1; off < 256; off <<= 1) {
        int addv = (t >= off) ? tsum[t - off] : 0;
        __syncthreads();
        tsum[t] += addv;
        __syncthreads();
    }
    int off0 = bsum[blockIdx.x] + (tsum[t] - s);
#pragma unroll
    for (int i = 0; i < 16; ++i) {
        int idx = base + i;
        if (idx < n) cnt[idx] = off0 + local[i];
    }
}

// nxt[i] = cnt[i]; bucket bases/cursors from rowStart. Grid covers [0, N].
__global__ __launch_bounds__(256) void csr_init_kernel(
    const int* __restrict__ cnt, int* __restrict__ nxt,
    int* __restrict__ bbase, int* __restrict__ cursor, int n)
{
    int i = blockIdx.x * 256 + threadIdx.x;
    if (i > n) return;
    nxt[i] = cnt[i];
    if (i <= NBUCK) {
        int v = i << 8;
        if (v > n) v = n;
        bbase[i] = cnt[v];
        if (i < NBUCK) cursor[i] = cnt[v];
    }
}

// Pass A: coarse bucket sort. Each block stages EPB edges, reserves
// bucket-contiguous runs, writes packed {src | dstlocal<<20, w}.
__global__ __launch_bounds__(256) void bucketA_kernel(
    const void* __restrict__ eidx, const float* __restrict__ ew,
    int* __restrict__ cursor, int2* __restrict__ packed, int nE)
{
    __shared__ int cnt[NBUCK];
    __shared__ int base[NBUCK];
    int t = threadIdx.x;
    for (int i = t; i < NBUCK; i += 256) cnt[i] = 0;
    __syncthreads();

    const int e0 = blockIdx.x * EPB;
    const int i64 = g_idx64;
    int lo[16]; float wv[16]; int bk[16];
#pragma unroll
    for (int i = 0; i < 16; ++i) {
        int e = e0 + t + i * 256;
        bk[i] = -1;
        if (e < nE) {
            int s, d;
            if (i64) {
                const long long* p = (const long long*)eidx;
                s = (int)p[e]; d = (int)p[nE + e];
            } else {
                const int* p = (const int*)eidx;
                s = p[e]; d = p[nE + e];
            }
            if ((unsigned)d < (unsigned)NN) {
                float w = ew[e];
                if ((unsigned)s >= (unsigned)NN) { s = 0; w = 0.f; }
                bk[i] = d >> 8;
                lo[i] = s | ((d & 255) << 20);
                wv[i] = w;
                atomicAdd(&cnt[bk[i]], 1);
            }
        }
    }
    __syncthreads();
    for (int i = t; i < NBUCK; i += 256)
        base[i] = (cnt[i] > 0) ? atomicAdd(&cursor[i], cnt[i]) : 0;
    __syncthreads();
    for (int i = t; i < NBUCK; i += 256) cnt[i] = 0;
    __syncthreads();
#pragma unroll
    for (int i = 0; i < 16; ++i) {
        if (bk[i] >= 0) {
            int r = atomicAdd(&cnt[bk[i]], 1);
            packed[base[bk[i]] + r] = make_int2(lo[i], __float_as_int(wv[i]));
        }
    }
}

// Pass B: one block per bucket; final CSR placement.
__global__ __launch_bounds__(256) void bucketB_kernel(
    const int2* __restrict__ packed, const int* __restrict__ bbase,
    int* __restrict__ nxt, int2* __restrict__ se)
{
    int b = blockIdx.x;
    int beg = bbase[b], end = bbase[b + 1];
    for (int p = beg + threadIdx.x; p < end; p += 256) {
        int2 e = packed[p];
        int src = e.x & 0xFFFFF;
        int dst = (b << 8) + ((e.x >> 20) & 255);
        int pos = atomicAdd(&nxt[dst], 1);
        se[pos] = make_int2(src, e.y);
    }
}

// ---------------- Aggregation: agg[n] = sum_e w_e * h[src_e] ---------------
__global__ __launch_bounds__(256) void gather_kernel(
    const int* __restrict__ rowStart, const int2* __restrict__ se,
    const float* __restrict__ h, float* __restrict__ agg, int nN)
{
    int t = blockIdx.x * 256 + threadIdx.x;
    int n = t >> 2;
    if (n >= nN) return;
    int c4 = t & 3;
    int beg = rowStart[n], end = rowStart[n + 1];
    const float4* h4 = (const float4*)h;
    float4 acc = make_float4(0.f, 0.f, 0.f, 0.f);
    for (int p = beg; p < end; ++p) {
        int2 e = se[p];
        float w = __int_as_float(e.y);
        float4 v = h4[(size_t)e.x * 4 + c4];
        acc.x = fmaf(w, v.x, acc.x);
        acc.y = fmaf(w, v.y, acc.y);
        acc.z = fmaf(w, v.z, acc.z);
        acc.w = fmaf(w, v.w, acc.w);
    }
    ((float4*)agg)[(size_t)n * 4 + c4] = acc;
}

// ---------------- h2 = relu(agg1 + b1) @ W2 --------------------------------
__global__ __launch_bounds__(256) void transform_kernel(
    const float* __restrict__ agg1, const float* __restrict__ b1,
    const float* __restrict__ W2, float* __restrict__ h2, int nN)
{
    __shared__ float sW2[256];
    __shared__ float sb1[16];
    sW2[threadIdx.x] = W2[threadIdx.x];
    if (threadIdx.x < 16) sb1[threadIdx.x] = b1[threadIdx.x];
    __syncthreads();
    int n = blockIdx.x * 256 + threadIdx.x;
    if (n >= nN) return;
    const float4* r = (const float4*)(agg1 + (size_t)n * 16);
    float v[16];
#pragma unroll
    for (int g = 0; g < 4; ++g) {
        float4 a = r[g];
        v[g * 4 + 0] = fmaxf(a.x + sb1[g * 4 + 0], 0.f);
        v[g * 4 + 1] = fmaxf(a.y + sb1[g * 4 + 1], 0.f);
        v[g * 4 + 2] = fmaxf(a.z + sb1[g * 4 + 2], 0.f);
        v[g * 4 + 3] = fmaxf(a.w + sb1[g * 4 + 3], 0.f);
    }
    float acc[16];
#pragma unroll
    for (int c = 0; c < 16; ++c) acc[c] = 0.f;
#pragma unroll
    for (int k = 0; k < 16; ++k) {
        float s = v[k];
#pragma unroll
        for (int c = 0; c < 16; ++c)
            acc[c] = fmaf(s, sW2[k * 16 + c], acc[c]);
    }
    float4* o = (float4*)(h2 + (size_t)n * 16);
#pragma unroll
    for (int g = 0; g < 4; ++g)
        o[g] = make_float4(acc[g * 4 + 0], acc[g * 4 + 1], acc[g * 4 + 2], acc[g * 4 + 3]);
}

// ---------------- out = log_softmax(agg2 + b2) -----------------------------
__global__ __launch_bounds__(256) void logsoftmax_kernel(
    const float* __restrict__ agg2, const float* __restrict__ b2,
    float* __restrict__ out, int nN)
{
    __shared__ float sb2[16];
    if (threadIdx.x < 16) sb2[threadIdx.x] = b2[threadIdx.x];
    __syncthreads();
    int n = blockIdx.x * 256 + threadIdx.x;
    if (n >= nN) return;
    const float4* r = (const float4*)(agg2 + (size_t)n * 16);
    float v[16];
#pragma unroll
    for (int g = 0; g < 4; ++g) {
        float4 a = r[g];
        v[g * 4 + 0] = a.x + sb2[g * 4 + 0];
        v[g * 4 + 1] = a.y + sb2[g * 4 + 1];
        v[g * 4 + 2] = a.z + sb2[g * 4 + 2];
        v[g * 4 + 3] = a.w + sb2[g * 4 + 3];
    }
    float m = v[0];
#pragma unroll
    for (int c = 1; c < 16; ++c) m = fmaxf(m, v[c]);
    float s = 0.f;
#pragma unroll
    for (int c = 0; c < 16; ++c) s += expf(v[c] - m);
    float l = m + logf(s);
    float4* o = (float4*)(out + (size_t)n * 16);
#pragma unroll
    for (int g = 0; g < 4; ++g)
        o[g] = make_float4(v[g * 4 + 0] - l, v[g * 4 + 1] - l,
                           v[g * 4 + 2] - l, v[g * 4 + 3] - l);
}

extern "C" void kernel_launch(void* const* d_in, const int* in_sizes, int n_in,
                              void* d_out, int out_size, void* d_ws, size_t ws_size,
                              hipStream_t stream)
{
    const float* x  = (const float*)d_in[0];
    const void*  ei = d_in[1];
    const float* ew = (const float*)d_in[2];
    const float* W1 = (const float*)d_in[3];
    const float* b1 = (const float*)d_in[4];
    const float* W2 = (const float*)d_in[5];
    const float* b2 = (const float*)d_in[6];
    float* out = (float*)d_out;

    const int N = NN;
    const int E = in_sizes[2];

    const size_t featB = (size_t)N * HID * sizeof(float);           // 6.4 MB
    const size_t rowB  = (((size_t)(N + 1) * 4) + 255) & ~255ULL;
    const size_t bkB   = (((size_t)(NBUCK + 1) * 4) + 255) & ~255ULL;
    const size_t seB   = ((size_t)E * 8 + 255) & ~255ULL;           // 25.6 MB

    char* w = (char*)d_ws;
    float* buf0 = (float*)w;      w += (featB + 255) & ~255ULL;
    float* buf1 = (float*)w;      w += (featB + 255) & ~255ULL;
    int*   rowStart = (int*)w;    w += rowB;
    int*   nxt = (int*)w;         w += rowB;
    int*   bbase = (int*)w;       w += bkB;
    int*   cursor = (int*)w;      w += bkB;
    int*   bsum = (int*)w;        w += 256;
    int2*  se = (int2*)w;         w += seB;
    int2*  packed = (int2*)w;     w += seB;

    detect_idx_kernel<<<1, 64, 0, stream>>>((const long long*)ei);
    gemm1_kernel<<<(N + 63) / 64, 64, 0, stream>>>(x, W1, buf0, N);

    const int eblocks = (E + 255) / 256;
    const int nblocks4 = (N * 4 + 255) / 256;

    // Bucketed CSR build with hierarchical scan.
    hipMemsetAsync(rowStart, 0, (size_t)(N + 1) * 4, stream);
    hist_kernel<<<eblocks, 256, 0, stream>>>(ei, rowStart, E);
    scanA_kernel<<<SBLOCKS, 256, 0, stream>>>(rowStart, bsum, N);
    scanB_kernel<<<1, 64, 0, stream>>>(bsum, rowStart, N, SBLOCKS);
    scanC_kernel<<<SBLOCKS, 256, 0, stream>>>(rowStart, bsum, N);
    csr_init_kernel<<<(N + 256) / 256, 256, 0, stream>>>(rowStart, nxt, bbase, cursor, N);
    bucketA_kernel<<<(E + EPB - 1) / EPB, 256, 0, stream>>>(ei, ew, cursor, packed, E);
    bucketB_kernel<<<NBUCK, 256, 0, stream>>>(packed, bbase, nxt, se);

    gather_kernel<<<nblocks4, 256, 0, stream>>>(rowStart, se, buf0, buf1, N);
    transform_kernel<<<(N + 255) / 256, 256, 0, stream>>>(buf1, b1, W2, buf0, N);
    gather_kernel<<<nblocks4, 256, 0, stream>>>(rowStart, se, buf0, buf1, N);
    logsoftmax_kernel<<<(N + 255) / 256, 256, 0, stream>>>(buf1, b2, out, N);
}

// Round 6
// 570.407 us; speedup vs baseline: 2.8831x; 1.2504x over previous
//
#include <hip/hip_runtime.h>
#include <math.h>

#define NN 100000
#define DF 512
#define HID 16
#define NBUCK 392            // ceil(NN/256) buckets of 256 dst values
#define EPB 4096             // edges per block in bucketA (256 thr x 16)

// Flag: 1 if edge_index is int64-laid-out, 0 if int32.
__device__ int g_idx64;

__global__ void detect_idx_kernel(const long long* __restrict__ idx) {
    int lane = threadIdx.x;  // 64 threads
    int ok = 1;
    for (int i = lane; i < 128; i += 64) {
        long long v = idx[i];
        if (v < 0 || v >= NN) ok = 0;
    }
    unsigned long long m = __ballot(ok);
    if (lane == 0) g_idx64 = (m == ~0ULL);
}

// ---------------- GEMM1: h1 = x @ W1 -------------------------------------
// One thread per node; W1 via wave-uniform scalar loads; x streamed float4.
__global__ __launch_bounds__(64) void gemm1_kernel(
    const float* __restrict__ x, const float* __restrict__ W1,
    float* __restrict__ h1, int nN)
{
    int node = blockIdx.x * 64 + threadIdx.x;
    if (node >= nN) return;
    const float4* xr = (const float4*)(x + (size_t)node * DF);

    float acc[16];
#pragma unroll
    for (int c = 0; c < 16; ++c) acc[c] = 0.f;

#pragma unroll 4
    for (int kq = 0; kq < DF / 4; ++kq) {
        float4 xv = xr[kq];
        const float* wrow = W1 + kq * 4 * HID;  // wave-uniform address
        float xs[4] = {xv.x, xv.y, xv.z, xv.w};
#pragma unroll
        for (int j = 0; j < 4; ++j) {
            float s = xs[j];
#pragma unroll
            for (int c = 0; c < 16; ++c)
                acc[c] = fmaf(s, wrow[j * 16 + c], acc[c]);
        }
    }

    float4* o = (float4*)(h1 + (size_t)node * HID);
#pragma unroll
    for (int g = 0; g < 4; ++g)
        o[g] = make_float4(acc[g * 4 + 0], acc[g * 4 + 1],
                           acc[g * 4 + 2], acc[g * 4 + 3]);
}

// ---------------- Bucket-level histogram (LDS-first) -----------------------
__global__ __launch_bounds__(256) void bucket_hist_kernel(
    const void* __restrict__ eidx, int* __restrict__ bcnt, int nE)
{
    __shared__ int h[NBUCK];
    for (int i = threadIdx.x; i < NBUCK; i += 256) h[i] = 0;
    __syncthreads();
    const int i64 = g_idx64;
    int stride = gridDim.x * 256;
    for (int e = blockIdx.x * 256 + threadIdx.x; e < nE; e += stride) {
        int d;
        if (i64) d = (int)((const long long*)eidx)[nE + e];
        else     d = ((const int*)eidx)[nE + e];
        if ((unsigned)d < (unsigned)NN) atomicAdd(&h[d >> 8], 1);
    }
    __syncthreads();
    for (int i = threadIdx.x; i < NBUCK; i += 256)
        if (h[i]) atomicAdd(&bcnt[i], h[i]);
}

// ---------------- Scan of 392 bucket counts -> bbase / cursor --------------
// One block, 512 threads. Also writes rowStart[NN] = total valid edges.
__global__ __launch_bounds__(512) void bucket_scan_kernel(
    const int* __restrict__ bcnt, int* __restrict__ bbase,
    int* __restrict__ cursor, int* __restrict__ rowStart)
{
    __shared__ int s[512];
    int t = threadIdx.x;
    int v = (t < NBUCK) ? bcnt[t] : 0;
    s[t] = v;
    __syncthreads();
    for (int off = 1; off < 512; off <<= 1) {
        int u = (t >= off) ? s[t - off] : 0;
        __syncthreads();
        s[t] += u;
        __syncthreads();
    }
    int excl = s[t] - v;   // exclusive prefix
    if (t < NBUCK) { bbase[t] = excl; cursor[t] = excl; }
    if (t == NBUCK) bbase[t] = excl;          // == total
    if (t == NBUCK) rowStart[NN] = excl;
}

// ---------------- Pass A: coarse bucket sort -------------------------------
__global__ __launch_bounds__(256) void bucketA_kernel(
    const void* __restrict__ eidx, const float* __restrict__ ew,
    int* __restrict__ cursor, int2* __restrict__ packed, int nE)
{
    __shared__ int cnt[NBUCK];
    __shared__ int base[NBUCK];
    int t = threadIdx.x;
    for (int i = t; i < NBUCK; i += 256) cnt[i] = 0;
    __syncthreads();

    const int e0 = blockIdx.x * EPB;
    const int i64 = g_idx64;
    int lo[16]; float wv[16]; int bk[16];
#pragma unroll
    for (int i = 0; i < 16; ++i) {
        int e = e0 + t + i * 256;
        bk[i] = -1;
        if (e < nE) {
            int s, d;
            if (i64) {
                const long long* p = (const long long*)eidx;
                s = (int)p[e]; d = (int)p[nE + e];
            } else {
                const int* p = (const int*)eidx;
                s = p[e]; d = p[nE + e];
            }
            if ((unsigned)d < (unsigned)NN) {
                float w = ew[e];
                if ((unsigned)s >= (unsigned)NN) { s = 0; w = 0.f; }
                bk[i] = d >> 8;
                lo[i] = s | ((d & 255) << 20);
                wv[i] = w;
                atomicAdd(&cnt[bk[i]], 1);
            }
        }
    }
    __syncthreads();
    for (int i = t; i < NBUCK; i += 256)
        base[i] = (cnt[i] > 0) ? atomicAdd(&cursor[i], cnt[i]) : 0;
    __syncthreads();
    for (int i = t; i < NBUCK; i += 256) cnt[i] = 0;
    __syncthreads();
#pragma unroll
    for (int i = 0; i < 16; ++i) {
        if (bk[i] >= 0) {
            int r = atomicAdd(&cnt[bk[i]], 1);
            packed[base[bk[i]] + r] = make_int2(lo[i], __float_as_int(wv[i]));
        }
    }
}

// ---------------- Pass B: per-bucket fine CSR (LDS hist + cursors) ---------
// One block per bucket: LDS histogram of 256 dst-locals, LDS scan -> this
// bucket's rowStart entries (coalesced), then placement via LDS cursors.
__global__ __launch_bounds__(256) void bucketB_kernel(
    const int2* __restrict__ packed, const int* __restrict__ bbase,
    int* __restrict__ rowStart, int2* __restrict__ se, int nN)
{
    __shared__ int hcnt[256];
    __shared__ int wtot[4];
    int b = blockIdx.x;
    int t = threadIdx.x;
    int beg = bbase[b], end = bbase[b + 1];

    hcnt[t] = 0;
    __syncthreads();
    for (int p = beg + t; p < end; p += 256)
        atomicAdd(&hcnt[(packed[p].x >> 20) & 255], 1);
    __syncthreads();

    // exclusive scan of hcnt[256]: shfl within waves + wave offsets
    int v = hcnt[t];
    int incl = v;
#pragma unroll
    for (int off = 1; off < 64; off <<= 1) {
        int u = __shfl_up(incl, off, 64);
        if ((t & 63) >= off) incl += u;
    }
    if ((t & 63) == 63) wtot[t >> 6] = incl;
    __syncthreads();
    int woff = 0;
#pragma unroll
    for (int w = 0; w < 4; ++w) if (w < (t >> 6)) woff += wtot[w];
    int excl = incl - v + woff;

    int node = b * 256 + t;
    if (node < nN) rowStart[node] = beg + excl;
    __syncthreads();
    hcnt[t] = beg + excl;   // reuse as cursor
    __syncthreads();

    for (int p = beg + t; p < end; p += 256) {
        int2 e = packed[p];
        int dl = (e.x >> 20) & 255;
        int pos = atomicAdd(&hcnt[dl], 1);
        se[pos] = make_int2(e.x & 0xFFFFF, e.y);
    }
}

// ---------------- Aggregation: agg[n] = sum_e w_e * h[src_e] ---------------
__global__ __launch_bounds__(256) void gather_kernel(
    const int* __restrict__ rowStart, const int2* __restrict__ se,
    const float* __restrict__ h, float* __restrict__ agg, int nN)
{
    int t = blockIdx.x * 256 + threadIdx.x;
    int n = t >> 2;
    if (n >= nN) return;
    int c4 = t & 3;
    int beg = rowStart[n], end = rowStart[n + 1];
    const float4* h4 = (const float4*)h;
    float4 acc = make_float4(0.f, 0.f, 0.f, 0.f);
    for (int p = beg; p < end; ++p) {
        int2 e = se[p];
        float w = __int_as_float(e.y);
        float4 v = h4[(size_t)e.x * 4 + c4];
        acc.x = fmaf(w, v.x, acc.x);
        acc.y = fmaf(w, v.y, acc.y);
        acc.z = fmaf(w, v.z, acc.z);
        acc.w = fmaf(w, v.w, acc.w);
    }
    ((float4*)agg)[(size_t)n * 4 + c4] = acc;
}

// ---------------- h2 = relu(agg1 + b1) @ W2 --------------------------------
__global__ __launch_bounds__(256) void transform_kernel(
    const float* __restrict__ agg1, const float* __restrict__ b1,
    const float* __restrict__ W2, float* __restrict__ h2, int nN)
{
    __shared__ float sW2[256];
    __shared__ float sb1[16];
    sW2[threadIdx.x] = W2[threadIdx.x];
    if (threadIdx.x < 16) sb1[threadIdx.x] = b1[threadIdx.x];
    __syncthreads();
    int n = blockIdx.x * 256 + threadIdx.x;
    if (n >= nN) return;
    const float4* r = (const float4*)(agg1 + (size_t)n * 16);
    float v[16];
#pragma unroll
    for (int g = 0; g < 4; ++g) {
        float4 a = r[g];
        v[g * 4 + 0] = fmaxf(a.x + sb1[g * 4 + 0], 0.f);
        v[g * 4 + 1] = fmaxf(a.y + sb1[g * 4 + 1], 0.f);
        v[g * 4 + 2] = fmaxf(a.z + sb1[g * 4 + 2], 0.f);
        v[g * 4 + 3] = fmaxf(a.w + sb1[g * 4 + 3], 0.f);
    }
    float acc[16];
#pragma unroll
    for (int c = 0; c < 16; ++c) acc[c] = 0.f;
#pragma unroll
    for (int k = 0; k < 16; ++k) {
        float s = v[k];
#pragma unroll
        for (int c = 0; c < 16; ++c)
            acc[c] = fmaf(s, sW2[k * 16 + c], acc[c]);
    }
    float4* o = (float4*)(h2 + (size_t)n * 16);
#pragma unroll
    for (int g = 0; g < 4; ++g)
        o[g] = make_float4(acc[g * 4 + 0], acc[g * 4 + 1], acc[g * 4 + 2], acc[g * 4 + 3]);
}

// ---------------- out = log_softmax(agg2 + b2) -----------------------------
__global__ __launch_bounds__(256) void logsoftmax_kernel(
    const float* __restrict__ agg2, const float* __restrict__ b2,
    float* __restrict__ out, int nN)
{
    __shared__ float sb2[16];
    if (threadIdx.x < 16) sb2[threadIdx.x] = b2[threadIdx.x];
    __syncthreads();
    int n = blockIdx.x * 256 + threadIdx.x;
    if (n >= nN) return;
    const float4* r = (const float4*)(agg2 + (size_t)n * 16);
    float v[16];
#pragma unroll
    for (int g = 0; g < 4; ++g) {
        float4 a = r[g];
        v[g * 4 + 0] = a.x + sb2[g * 4 + 0];
        v[g * 4 + 1] = a.y + sb2[g * 4 + 1];
        v[g * 4 + 2] = a.z + sb2[g * 4 + 2];
        v[g * 4 + 3] = a.w + sb2[g * 4 + 3];
    }
    float m = v[0];
#pragma unroll
    for (int c = 1; c < 16; ++c) m = fmaxf(m, v[c]);
    float s = 0.f;
#pragma unroll
    for (int c = 0; c < 16; ++c) s += expf(v[c] - m);
    float l = m + logf(s);
    float4* o = (float4*)(out + (size_t)n * 16);
#pragma unroll
    for (int g = 0; g < 4; ++g)
        o[g] = make_float4(v[g * 4 + 0] - l, v[g * 4 + 1] - l,
                           v[g * 4 + 2] - l, v[g * 4 + 3] - l);
}

extern "C" void kernel_launch(void* const* d_in, const int* in_sizes, int n_in,
                              void* d_out, int out_size, void* d_ws, size_t ws_size,
                              hipStream_t stream)
{
    const float* x  = (const float*)d_in[0];
    const void*  ei = d_in[1];
    const float* ew = (const float*)d_in[2];
    const float* W1 = (const float*)d_in[3];
    const float* b1 = (const float*)d_in[4];
    const float* W2 = (const float*)d_in[5];
    const float* b2 = (const float*)d_in[6];
    float* out = (float*)d_out;

    const int N = NN;
    const int E = in_sizes[2];

    const size_t featB = (size_t)N * HID * sizeof(float);           // 6.4 MB
    const size_t rowB  = (((size_t)(N + 1) * 4) + 255) & ~255ULL;
    const size_t bkB   = (((size_t)(NBUCK + 1) * 4) + 255) & ~255ULL;
    const size_t seB   = ((size_t)E * 8 + 255) & ~255ULL;           // 25.6 MB

    char* w = (char*)d_ws;
    float* buf0 = (float*)w;      w += (featB + 255) & ~255ULL;
    float* buf1 = (float*)w;      w += (featB + 255) & ~255ULL;
    int*   rowStart = (int*)w;    w += rowB;
    int*   bcnt = (int*)w;        w += bkB;
    int*   bbase = (int*)w;       w += bkB;
    int*   cursor = (int*)w;      w += bkB;
    int2*  se = (int2*)w;         w += seB;
    int2*  packed = (int2*)w;     w += seB;

    detect_idx_kernel<<<1, 64, 0, stream>>>((const long long*)ei);
    gemm1_kernel<<<(N + 63) / 64, 64, 0, stream>>>(x, W1, buf0, N);

    const int nblocks4 = (N * 4 + 255) / 256;

    // Bucketed CSR build: LDS-first histogram, tiny scan, per-bucket fine CSR.
    hipMemsetAsync(bcnt, 0, (size_t)NBUCK * 4, stream);
    bucket_hist_kernel<<<256, 256, 0, stream>>>(ei, bcnt, E);
    bucket_scan_kernel<<<1, 512, 0, stream>>>(bcnt, bbase, cursor, rowStart);
    bucketA_kernel<<<(E + EPB - 1) / EPB, 256, 0, stream>>>(ei, ew, cursor, packed, E);
    bucketB_kernel<<<NBUCK, 256, 0, stream>>>(packed, bbase, rowStart, se, N);

    gather_kernel<<<nblocks4, 256, 0, stream>>>(rowStart, se, buf0, buf1, N);
    transform_kernel<<<(N + 255) / 256, 256, 0, stream>>>(buf1, b1, W2, buf0, N);
    gather_kernel<<<nblocks4, 256, 0, stream>>>(rowStart, se, buf0, buf1, N);
    logsoftmax_kernel<<<(N + 255) / 256, 256, 0, stream>>>(buf1, b2, out, N);
}